// Round 9
// baseline (1589.146 us; speedup 1.0000x reference)
//
#include <hip/hip_runtime.h>
#include <hip/hip_bf16.h>

#define NN 50000
#define NPAD 50048   // h rows incl. zero rows 50000..50047
#define EE 1600000
#define NB 391       // buckets of 128 rows
#define CAPB 4608    // per-bucket record capacity (mean 4092, +8 sigma)
#define CPAD 16      // one counter per 64B line
#define PBCAP 7424   // padded CSR slots per bucket (mean 5939, +8 sigma)
#define GRID 1024    // 256 CUs x 4 blocks/CU co-resident (launch_bounds enforced)
#define EPB2 1564    // edges per bucket-phase block: 1024*1564 >= EE, %4==0
#define BCAP2 16     // per-(block,bucket) LDS cap; mean 4.0 (+6 sigma, spill-safe)

typedef __attribute__((ext_vector_type(8))) short short8;
typedef __attribute__((ext_vector_type(4))) float floatx4;

__device__ __forceinline__ float ldext(const void* p, long i, int f32) {
    return f32 ? ((const float*)p)[i]
               : __bfloat162float(((const __hip_bfloat16*)p)[i]);
}
__device__ __forceinline__ unsigned short f2b(float f) {
    __hip_bfloat16 h = __float2bfloat16(f);   // round-to-nearest-even
    unsigned short u; __builtin_memcpy(&u, &h, 2); return u;
}
__device__ __forceinline__ float asf(unsigned int v) {
    float f; __builtin_memcpy(&f, &v, 4); return f;
}

// LDS union across phases (max 26.6 KB; 4 blocks/CU -> 108 KB < 160 KB)
struct SB { int lcnt[NB]; int dcnt; unsigned binned[NB * BCAP2]; };
struct SC { unsigned recs[CAPB]; int cnt[128]; int incl[128]; int curs[128]; };
struct SG { unsigned short xs[64 * 72]; unsigned short wt[64 * 72]; };

// Grid barrier: monotonic arrival counter, device-scope fences for cross-XCD
// visibility (per-XCD L2s are non-coherent; release flushes, acquire invalidates).
// Bounded spin: on pathological stall we break (fail-visible), never hang.
__device__ __forceinline__ void gbar(int* bar, int target) {
    __syncthreads();                      // block done
    if (threadIdx.x == 0) {
        __threadfence();                  // release: flush this block's writes
        __hip_atomic_fetch_add(bar, 1, __ATOMIC_RELAXED, __HIP_MEMORY_SCOPE_AGENT);
        int spins = 0;
        while (__hip_atomic_load(bar, __ATOMIC_RELAXED, __HIP_MEMORY_SCOPE_AGENT) < target) {
            __builtin_amdgcn_s_sleep(2);
            if (++spins > (1 << 27)) break;   // fail-visible escape
        }
    }
    __syncthreads();
    __threadfence();                      // acquire: invalidate stale caches
}

// ---------------- dense h' = dis_n * (X @ W), MFMA bf16, W staged in LDS ----
template <bool EXT>
__device__ __forceinline__ void gemm_phase(unsigned char* smem, const void* __restrict__ X,
                                           const void* __restrict__ W,
                                           const int* __restrict__ flag,
                                           const float* __restrict__ dis,
                                           unsigned short* __restrict__ Hout) {
    SG& sg = *(SG*)smem;
    int tid = threadIdx.x;
    const int f32 = flag[0];
    const unsigned short* Wb = (const unsigned short*)W;
    const float* Wf = (const float*)W;
    for (int vb = blockIdx.x; vb < NPAD / 64; vb += GRID) {
        int n0 = vb * 64;
        for (int idx = tid; idx < 4096; idx += 256) {
            int nn = idx >> 6, k = idx & 63;
            int n = n0 + nn;
            unsigned short v = 0;
            if (n < NN) {
                long ofs = (long)n * 64 + k;
                if (EXT) v = f32 ? f2b(((const float*)X)[ofs]) : ((const unsigned short*)X)[ofs];
                else     v = ((const unsigned short*)X)[ofs];
            }
            sg.xs[nn * 72 + k] = v;
            int wk = idx >> 6, wn = idx & 63;
            sg.wt[wn * 72 + wk] = f32 ? f2b(Wf[idx]) : Wb[idx];
        }
        __syncthreads();
        int lane = tid & 63, wid = tid >> 6;
        int m0 = wid * 16;
        int quad = lane >> 4, nl = lane & 15;
        short8 a0 = *(const short8*)(sg.xs + (m0 + nl) * 72 + quad * 8);
        short8 a1 = *(const short8*)(sg.xs + (m0 + nl) * 72 + quad * 8 + 32);
        floatx4 acc[4];
        #pragma unroll
        for (int ct = 0; ct < 4; ++ct) {
            int n = ct * 16 + nl;
            short8 b0 = *(const short8*)(sg.wt + n * 72 + quad * 8);
            short8 b1 = *(const short8*)(sg.wt + n * 72 + quad * 8 + 32);
            floatx4 c = {0.f, 0.f, 0.f, 0.f};
            c = __builtin_amdgcn_mfma_f32_16x16x32_bf16(a0, b0, c, 0, 0, 0);
            c = __builtin_amdgcn_mfma_f32_16x16x32_bf16(a1, b1, c, 0, 0, 0);
            acc[ct] = c;
        }
        #pragma unroll
        for (int r = 0; r < 4; ++r) {
            int node = n0 + m0 + quad * 4 + r;   // always < NPAD
            if (node < NN) {
                float dn = dis[node];
                #pragma unroll
                for (int ct = 0; ct < 4; ++ct)
                    Hout[(long)node * 64 + ct * 16 + nl] = f2b(dn * acc[ct][r]);
            } else {
                #pragma unroll
                for (int ct = 0; ct < 4; ++ct)
                    Hout[(long)node * 64 + ct * 16 + nl] = 0;
            }
        }
        __syncthreads();    // LDS reuse guard if looped
    }
}

// ---------------- per-node aggregation + bias + relu + l2norm ----------------
__device__ __forceinline__ void agg_phase(const uint4* __restrict__ hp128,
                                          const int* __restrict__ rp0,
                                          const int* __restrict__ degA,
                                          const float* __restrict__ dis,
                                          const unsigned short* __restrict__ csr_col,
                                          const void* __restrict__ bias,
                                          const int* __restrict__ flag,
                                          unsigned short* __restrict__ eo) {
    int lane = threadIdx.x & 63, wid = threadIdx.x >> 6;
    int half = lane >> 5;
    int q4 = (lane >> 3) & 3;   // edge-slot octet within half
    int fl = lane & 7;          // feature octet
    const int f32 = flag[0];
    for (int vb = blockIdx.x; vb < (NN + 7) / 8; vb += GRID) {
        int i = vb * 8 + wid * 2 + half;
        bool valid = (i < NN);
        int iv = valid ? i : 0;
        float2 A0 = {0,0}, A1 = {0,0}, A2 = {0,0}, A3 = {0,0};
        #define ADDU(u) do { \
            A0.x += asf((u).x << 16); A0.y += asf((u).x & 0xFFFF0000u); \
            A1.x += asf((u).y << 16); A1.y += asf((u).y & 0xFFFF0000u); \
            A2.x += asf((u).z << 16); A2.y += asf((u).z & 0xFFFF0000u); \
            A3.x += asf((u).w << 16); A3.y += asf((u).w & 0xFFFF0000u); } while (0)
        if (valid && q4 == 0) {     // self-loop term
            uint4 u = hp128[(long)iv * 8 + fl];
            ADDU(u);
        }
        int e0 = rp0[iv];
        int pd = (degA[iv] + 31) & ~31;
        const unsigned short* cb = csr_col + e0 + q4 * 8;
        for (int t = 0; t < pd; t += 32) {
            uint4 I = *(const uint4*)(cb + t);
            int c0 = (int)(I.x & 0xFFFFu), c1 = (int)(I.x >> 16);
            int c2 = (int)(I.y & 0xFFFFu), c3 = (int)(I.y >> 16);
            int c4 = (int)(I.z & 0xFFFFu), c5 = (int)(I.z >> 16);
            int c6 = (int)(I.w & 0xFFFFu), c7 = (int)(I.w >> 16);
            uint4 u0 = hp128[(long)c0 * 8 + fl];
            uint4 u1 = hp128[(long)c1 * 8 + fl];
            uint4 u2 = hp128[(long)c2 * 8 + fl];
            uint4 u3 = hp128[(long)c3 * 8 + fl];
            uint4 u4 = hp128[(long)c4 * 8 + fl];
            uint4 u5 = hp128[(long)c5 * 8 + fl];
            uint4 u6 = hp128[(long)c6 * 8 + fl];
            uint4 u7 = hp128[(long)c7 * 8 + fl];
            ADDU(u0); ADDU(u1); ADDU(u2); ADDU(u3);
            ADDU(u4); ADDU(u5); ADDU(u6); ADDU(u7);
        }
        #undef ADDU
        #pragma unroll
        for (int off = 8; off < 32; off <<= 1) {
            A0.x += __shfl_xor(A0.x, off); A0.y += __shfl_xor(A0.y, off);
            A1.x += __shfl_xor(A1.x, off); A1.y += __shfl_xor(A1.y, off);
            A2.x += __shfl_xor(A2.x, off); A2.y += __shfl_xor(A2.y, off);
            A3.x += __shfl_xor(A3.x, off); A3.y += __shfl_xor(A3.y, off);
        }
        float di = dis[iv];
        float v0 = fmaf(di, A0.x, ldext(bias, 8 * fl + 0, f32));
        float v1 = fmaf(di, A0.y, ldext(bias, 8 * fl + 1, f32));
        float v2 = fmaf(di, A1.x, ldext(bias, 8 * fl + 2, f32));
        float v3 = fmaf(di, A1.y, ldext(bias, 8 * fl + 3, f32));
        float v4 = fmaf(di, A2.x, ldext(bias, 8 * fl + 4, f32));
        float v5 = fmaf(di, A2.y, ldext(bias, 8 * fl + 5, f32));
        float v6 = fmaf(di, A3.x, ldext(bias, 8 * fl + 6, f32));
        float v7 = fmaf(di, A3.y, ldext(bias, 8 * fl + 7, f32));
        v0 = fmaxf(v0, 0.f); v1 = fmaxf(v1, 0.f); v2 = fmaxf(v2, 0.f); v3 = fmaxf(v3, 0.f);
        v4 = fmaxf(v4, 0.f); v5 = fmaxf(v5, 0.f); v6 = fmaxf(v6, 0.f); v7 = fmaxf(v7, 0.f);
        float s = fmaf(v0, v0, fmaf(v1, v1, fmaf(v2, v2, v3 * v3)))
                + fmaf(v4, v4, fmaf(v5, v5, fmaf(v6, v6, v7 * v7)));
        #pragma unroll
        for (int off = 4; off; off >>= 1) s += __shfl_xor(s, off);
        float inv = 1.f / fmaxf(sqrtf(s), 1e-12f);
        if (valid && q4 == 0) {
            union { unsigned short us[8]; uint4 v; } pk;
            pk.us[0] = f2b(v0 * inv); pk.us[1] = f2b(v1 * inv);
            pk.us[2] = f2b(v2 * inv); pk.us[3] = f2b(v3 * inv);
            pk.us[4] = f2b(v4 * inv); pk.us[5] = f2b(v5 * inv);
            pk.us[6] = f2b(v6 * inv); pk.us[7] = f2b(v7 * inv);
            *(uint4*)(eo + (long)i * 64 + 8 * fl) = pk.v;
        }
    }
}

// ---------------- head: emb @ Wlin + blin + log_softmax, MFMA ----------------
__device__ __forceinline__ void out_phase(const unsigned short* __restrict__ emb,
                                          const void* __restrict__ Wlin,
                                          const void* __restrict__ blin,
                                          const int* __restrict__ flag,
                                          void* __restrict__ outp) {
    int tid = threadIdx.x, lane = tid & 63, wid = tid >> 6;
    int quad = lane >> 4, nl = lane & 15;
    const int f32 = flag[0];
    const unsigned short* Wb = (const unsigned short*)Wlin;
    const float* Wf = (const float*)Wlin;
    for (int vb = blockIdx.x; vb < NPAD / 64; vb += GRID) {
        int base = vb * 64 + wid * 16;
        int ia = min(base + nl, NN - 1);
        floatx4 c = {0.f, 0.f, 0.f, 0.f};
        #pragma unroll
        for (int kc = 0; kc < 6; ++kc) {
            short8 b;
            #pragma unroll
            for (int j = 0; j < 8; ++j) {
                int k = kc * 32 + quad * 8 + j;
                b[j] = (short)(f32 ? f2b(Wf[k * 16 + nl]) : Wb[k * 16 + nl]);
            }
            int L = kc >> 1, ko = (kc & 1) * 32 + quad * 8;
            short8 a = *(const short8*)(emb + (long)L * NN * 64 + (long)ia * 64 + ko);
            c = __builtin_amdgcn_mfma_f32_16x16x32_bf16(a, b, c, 0, 0, 0);
        }
        float bl = ldext(blin, nl, f32);
        #pragma unroll
        for (int r = 0; r < 4; ++r) {
            float v = c[r] + bl;
            float m = v;
            #pragma unroll
            for (int off = 1; off < 16; off <<= 1) m = fmaxf(m, __shfl_xor(m, off));
            float ex = __expf(v - m);
            float s = ex;
            #pragma unroll
            for (int off = 1; off < 16; off <<= 1) s += __shfl_xor(s, off);
            float o = (v - m) - __logf(s);
            int node = base + quad * 4 + r;
            if (node < NN) {
                long oidx = (long)node * 16 + nl;
                if (f32) ((float*)outp)[oidx] = o;
                else     ((__hip_bfloat16*)outp)[oidx] = __float2bfloat16(o);
            }
        }
    }
}

// ---------------- the whole pipeline: ONE persistent kernel, 8 grid barriers --
extern "C" __global__ void __launch_bounds__(256, 4)
k_mega(const void* __restrict__ x, const int* __restrict__ ei,
       const void* __restrict__ W1, const void* __restrict__ b1,
       const void* __restrict__ W2, const void* __restrict__ b2,
       const void* __restrict__ W3, const void* __restrict__ b3,
       const void* __restrict__ Wlin, const void* __restrict__ blin,
       void* __restrict__ outp,
       unsigned short* __restrict__ h, unsigned short* __restrict__ emb,
       float* __restrict__ dis, int* __restrict__ rp0, int* __restrict__ degA,
       int* __restrict__ flag, int* __restrict__ bar,
       int* __restrict__ bcur, unsigned* __restrict__ bdata,
       unsigned short* __restrict__ csr_col) {
    __shared__ __align__(16) unsigned char smem[27648];
    int tid = threadIdx.x;
    const int* row = ei;        // edge_index[0] = targets
    const int* col = ei + EE;   // edge_index[1] = sources

    // ---- phase 0: bucket binning (+dtype flag in block 0) ----
    {
        SB& sb = *(SB*)smem;
        if (blockIdx.x == 0) {
            if (tid == 0) sb.dcnt = 0;
            __syncthreads();
            int local = 0;
            const unsigned short* xu = (const unsigned short*)x;
            for (int j = 0; j < 16; ++j) {
                unsigned short u = xu[2 * (tid + 256 * j)];
                int ex = (u >> 7) & 0xFF;
                if (ex == 0xFF || ex < 0x60) local++;
            }
            atomicAdd(&sb.dcnt, local);
            __syncthreads();
            if (tid == 0) flag[0] = (sb.dcnt > 256) ? 1 : 0;
        }
        long base = (long)blockIdx.x * EPB2;
        int nedge = (int)min((long)EPB2, (long)EE - base);   // %4 == 0
        for (int k = tid; k < NB; k += 256) sb.lcnt[k] = 0;
        __syncthreads();
        const int4* r4 = (const int4*)(row + base);
        const int4* c4 = (const int4*)(col + base);
        for (int j = tid; j < (nedge >> 2); j += 256) {
            int4 rr = r4[j], cc = c4[j];
            #pragma unroll
            for (int t = 0; t < 4; ++t) {
                int r = (&rr.x)[t], c = (&cc.x)[t];
                int b = r >> 7;
                unsigned rec = ((unsigned)(r & 127) << 16) | (unsigned)c;
                int p = atomicAdd(&sb.lcnt[b], 1);
                if (p < BCAP2) sb.binned[b * BCAP2 + p] = rec;
                else {                               // rare spill
                    int gp = atomicAdd(&bcur[b * CPAD], 1);
                    if (gp < CAPB) bdata[(long)b * CAPB + gp] = rec;
                }
            }
        }
        __syncthreads();
        for (int b = tid; b < NB; b += 256) {
            int n = min(sb.lcnt[b], BCAP2);
            if (!n) continue;
            int gb = atomicAdd(&bcur[b * CPAD], n);
            long dst = (long)b * CAPB;
            for (int j = 0; j < n; ++j)
                if (gb + j < CAPB) bdata[dst + gb + j] = sb.binned[b * BCAP2 + j];
        }
    }
    int tgt = GRID;
    gbar(bar, tgt); tgt += GRID;

    // ---- phase 1: degree count + padded CSR build (bucket-local regions) ----
    if (blockIdx.x < NB) {
        SC& sc = *(SC*)smem;
        int b = blockIdx.x;
        int lane = tid & 63, wid = tid >> 6;
        if (tid < 128) sc.cnt[tid] = 0;
        __syncthreads();
        int n = min(bcur[b * CPAD], CAPB);
        const unsigned* dp = bdata + (long)b * CAPB;
        for (int i = tid; i < n; i += 256) {
            unsigned rec = dp[i];
            sc.recs[i] = rec;
            atomicAdd(&sc.cnt[(rec >> 16) & 127], 1);
        }
        __syncthreads();
        if (tid < 128) {
            int xx = (sc.cnt[tid] + 31) & ~31;       // padded degree
            #pragma unroll
            for (int off = 1; off < 64; off <<= 1) {
                int y = __shfl_up(xx, off);
                if (lane >= off) xx += y;
            }
            sc.incl[tid] = xx;
        }
        __syncthreads();
        int r0 = b << 7;
        int lim = (b + 1) * PBCAP;
        if (tid < 128) {
            int c = sc.cnt[tid];
            int xx = (c + 31) & ~31;
            int ic = sc.incl[tid] + (wid == 1 ? sc.incl[63] : 0);
            int excl = b * PBCAP + ic - xx;
            sc.curs[tid] = excl;
            int r = r0 + tid;
            if (r < NN) {
                rp0[r] = excl;
                degA[r] = c;
                dis[r] = rsqrtf((float)(c + 1));
            }
            for (int j = c; j < xx && excl + j < lim; ++j)
                csr_col[excl + j] = (unsigned short)NN;   // pad -> zero row
        }
        __syncthreads();
        for (int i = tid; i < n; i += 256) {
            unsigned rec = sc.recs[i];
            int p = atomicAdd(&sc.curs[(rec >> 16) & 127], 1);
            if (p < lim) csr_col[p] = (unsigned short)(rec & 0xFFFF);
        }
    }
    gbar(bar, tgt); tgt += GRID;

    const uint4* hp128 = (const uint4*)h;
    // ---- layer 1 ----
    gemm_phase<true>(smem, x, W1, flag, dis, h);
    gbar(bar, tgt); tgt += GRID;
    agg_phase(hp128, rp0, degA, dis, csr_col, b1, flag, emb);
    gbar(bar, tgt); tgt += GRID;
    // ---- layer 2 ----
    gemm_phase<false>(smem, emb, W2, flag, dis, h);
    gbar(bar, tgt); tgt += GRID;
    agg_phase(hp128, rp0, degA, dis, csr_col, b2, flag, emb + (long)NN * 64);
    gbar(bar, tgt); tgt += GRID;
    // ---- layer 3 ----
    gemm_phase<false>(smem, emb + (long)NN * 64, W3, flag, dis, h);
    gbar(bar, tgt); tgt += GRID;
    agg_phase(hp128, rp0, degA, dis, csr_col, b3, flag, emb + (long)2 * NN * 64);
    gbar(bar, tgt); tgt += GRID;
    // ---- head ----
    out_phase(emb, Wlin, blin, flag, outp);
}

extern "C" void kernel_launch(void* const* d_in, const int* in_sizes, int n_in,
                              void* d_out, int out_size, void* d_ws, size_t ws_size,
                              hipStream_t stream) {
    const void* x    = d_in[0];
    const int*  ei   = (const int*)d_in[1];
    const void* W1   = d_in[2];
    const void* b1   = d_in[3];
    const void* W2   = d_in[4];
    const void* b2   = d_in[5];
    const void* W3   = d_in[6];
    const void* b3   = d_in[7];
    const void* Wlin = d_in[8];
    const void* blin = d_in[9];

    // workspace layout (~39.3 MB)
    unsigned short* h   = (unsigned short*)d_ws;      // NPAD*64 bf16 (rows >=NN zero)
    unsigned short* emb = h + (long)NPAD * 64;        // 3 x N*64 bf16
    float* dis     = (float*)(emb + (long)3 * NN * 64); // N
    int*   rp0     = (int*)(dis + NN);                // N
    int*   degA    = rp0 + NN;                        // N
    int*   flag    = degA + NN;                       // 16
    int*   bar     = flag + 16;                       // 16 (barrier counter)
    int*   bcur    = bar + 16;                        // NB*CPAD
    unsigned* bdata = (unsigned*)(bcur + NB * CPAD);  // NB*CAPB u32
    unsigned short* csr_col = (unsigned short*)(bdata + (long)NB * CAPB); // NB*PBCAP u16

    // zero barrier counter + bucket cursors in one memset
    (void)hipMemsetAsync(bar, 0, (16 + NB * CPAD) * sizeof(int), stream);
    k_mega<<<GRID, 256, 0, stream>>>(x, ei, W1, b1, W2, b2, W3, b3, Wlin, blin,
                                     d_out, h, emb, dis, rp0, degA, flag, bar,
                                     bcur, bdata, csr_col);
}

// Round 10
// 259.708 us; speedup vs baseline: 6.1190x; 6.1190x over previous
//
#include <hip/hip_runtime.h>
#include <hip/hip_bf16.h>

#define NN 50000
#define NPAD 50048   // h rows incl. zero rows 50000..50047 (gemm grid coverage)
#define EE 1600000
#define NB 391       // buckets of 128 rows
#define CAPB 4608    // per-bucket record capacity (mean 4092, +8 sigma)
#define CPAD 16      // one counter per 64B line
#define EPB 4096     // edges per k_bucket block -> 391 blocks
#define BCAP 29      // per-(block,bucket) LDS cap; odd -> conflict-free bank spread
#define PBCAP 7424   // padded CSR slots per bucket (mean 5939, +8 sigma)

typedef __attribute__((ext_vector_type(8))) short short8;
typedef __attribute__((ext_vector_type(4))) float floatx4;

// ---- dual-dtype load: external float tensors are either f32 or bf16 (flag).
__device__ __forceinline__ float ldext(const void* p, long i, int f32) {
    return f32 ? ((const float*)p)[i]
               : __bfloat162float(((const __hip_bfloat16*)p)[i]);
}

__device__ __forceinline__ unsigned short f2b(float f) {
    __hip_bfloat16 h = __float2bfloat16(f);   // round-to-nearest-even
    unsigned short u; __builtin_memcpy(&u, &h, 2); return u;
}
__device__ __forceinline__ float asf(unsigned int x) {
    float f; __builtin_memcpy(&f, &x, 4); return f;
}

// ---------------- pass A: LDS binning + lane-parallel flush (+flag in blk 0) --
__global__ void k_bucket(const int* __restrict__ row, const int* __restrict__ col,
                         int* __restrict__ bcur, unsigned int* __restrict__ bdata,
                         const unsigned short* __restrict__ xu, int* __restrict__ flag) {
    __shared__ int lcnt[NB];
    __shared__ unsigned binned[NB * BCAP];   // ~45.4 KB
    __shared__ int dcnt;
    int tid = threadIdx.x;
    if (blockIdx.x == 0) {                   // input-dtype detection (once)
        if (tid == 0) dcnt = 0;
        __syncthreads();
        int local = 0;
        for (int j = 0; j < 16; ++j) {
            unsigned short u = xu[2 * (tid + 256 * j)];
            int ex = (u >> 7) & 0xFF;
            if (ex == 0xFF || ex < 0x60) local++;
        }
        atomicAdd(&dcnt, local);
        __syncthreads();
        if (tid == 0) flag[0] = (dcnt > 256) ? 1 : 0;
    }
    long base = (long)blockIdx.x * EPB;
    int nedge = (int)min((long)EPB, (long)EE - base);   // always multiple of 4
    for (int k = tid; k < NB; k += 256) lcnt[k] = 0;
    __syncthreads();
    const int4* r4 = (const int4*)(row + base);
    const int4* c4 = (const int4*)(col + base);
    for (int j = tid; j < (nedge >> 2); j += 256) {
        int4 rr = r4[j], cc = c4[j];
        #pragma unroll
        for (int t = 0; t < 4; ++t) {
            int r = (&rr.x)[t], c = (&cc.x)[t];
            int b = r >> 7;
            unsigned rec = ((unsigned)(r & 127) << 16) | (unsigned)c;
            int p = atomicAdd(&lcnt[b], 1);
            if (p < BCAP) binned[b * BCAP + p] = rec;
            else {                               // rare spill: direct global append
                int gp = atomicAdd(&bcur[b * CPAD], 1);
                if (gp < CAPB) bdata[(long)b * CAPB + gp] = rec;
            }
        }
    }
    __syncthreads();
    for (int b = tid; b < NB; b += 256) {
        int n = min(lcnt[b], BCAP);
        if (!n) continue;
        int gb = atomicAdd(&bcur[b * CPAD], n);
        long dst = (long)b * CAPB;
        for (int j = 0; j < n; ++j)
            if (gb + j < CAPB) bdata[dst + gb + j] = binned[b * BCAP + j];
    }
}

// ---------------- fused: degree count + padded CSR build ---------------------
// Per-bucket FIXED region [b*PBCAP, (b+1)*PBCAP): no cross-bucket prefix.
// Each node's edge list padded to a multiple of 32 slots with index NN (the
// zero row): k_agg's inner loop needs no per-slot bounds checks.
__global__ void k_csr(const int* __restrict__ bcur, const unsigned* __restrict__ bdata,
                      int* __restrict__ rp0, int* __restrict__ degA,
                      float* __restrict__ dis, unsigned short* __restrict__ csr_col) {
    __shared__ unsigned recs[CAPB];          // 18.4 KB
    __shared__ int cnt[128];
    __shared__ int incl[128];
    __shared__ int curs[128];
    int b = blockIdx.x, tid = threadIdx.x;
    int lane = tid & 63, wid = tid >> 6;
    if (tid < 128) cnt[tid] = 0;
    __syncthreads();
    int n = min(bcur[b * CPAD], CAPB);
    const unsigned* dp = bdata + (long)b * CAPB;
    for (int i = tid; i < n; i += 256) {
        unsigned rec = dp[i];
        recs[i] = rec;
        atomicAdd(&cnt[(rec >> 16) & 127], 1);
    }
    __syncthreads();
    if (tid < 128) {
        int x = (cnt[tid] + 31) & ~31;       // padded degree
        #pragma unroll
        for (int off = 1; off < 64; off <<= 1) {
            int y = __shfl_up(x, off);
            if (lane >= off) x += y;
        }
        incl[tid] = x;
    }
    __syncthreads();
    int r0 = b << 7;
    int lim = (b + 1) * PBCAP;
    if (tid < 128) {
        int c = cnt[tid];
        int x = (c + 31) & ~31;
        int ic = incl[tid] + (wid == 1 ? incl[63] : 0);
        int excl = b * PBCAP + ic - x;
        curs[tid] = excl;
        int r = r0 + tid;
        if (r < NN) {
            rp0[r] = excl;
            degA[r] = c;
            dis[r] = rsqrtf((float)(c + 1));
        }
        for (int j = c; j < x && excl + j < lim; ++j)
            csr_col[excl + j] = (unsigned short)NN;   // pad -> zero row
    }
    __syncthreads();
    for (int i = tid; i < n; i += 256) {
        unsigned rec = recs[i];
        int p = atomicAdd(&curs[(rec >> 16) & 127], 1);
        if (p < lim) csr_col[p] = (unsigned short)(rec & 0xFFFF);
    }
}

// ---------------- dense h' = dis_n * (X @ W), MFMA bf16 ---------------------
// VECTOR staging: X rows as short8 (bf16) / float4 (f32); W staged transposed
// via wide loads + LDS scatter. Rows NN..NPAD-1 written as zeros (pad target).
template <bool EXT>
__global__ void k_gemm(const void* __restrict__ X, const void* __restrict__ W,
                       const int* __restrict__ flag, const float* __restrict__ dis,
                       unsigned short* __restrict__ Hout) {
    __shared__ __align__(16) unsigned short xs[64 * 72];
    __shared__ __align__(16) unsigned short wt[64 * 72];  // W transposed: wt[n*72+k]
    int tid = threadIdx.x;
    int n0 = blockIdx.x * 64;
    const int f32 = flag[0];
    const unsigned short* Wb = (const unsigned short*)W;
    const float* Wf = (const float*)W;
    // --- stage X tile (vectorized) ---
    if (EXT && f32) {
        for (int idx = tid; idx < 1024; idx += 256) {
            int nn = idx >> 4, sg = idx & 15;
            int n = n0 + nn;
            float4 v = {0.f, 0.f, 0.f, 0.f};
            if (n < NN) v = *(const float4*)((const float*)X + (long)n * 64 + sg * 4);
            ushort4 s;
            s.x = f2b(v.x); s.y = f2b(v.y); s.z = f2b(v.z); s.w = f2b(v.w);
            *(ushort4*)(xs + nn * 72 + sg * 4) = s;   // 8B-aligned (144*nn+8*sg)
        }
    } else {
        for (int idx = tid; idx < 512; idx += 256) {
            int nn = idx >> 3, sg = idx & 7;
            int n = n0 + nn;
            short8 v = {0, 0, 0, 0, 0, 0, 0, 0};
            if (n < NN) v = *(const short8*)((const unsigned short*)X + (long)n * 64 + sg * 8);
            *(short8*)(xs + nn * 72 + sg * 8) = v;    // 16B-aligned (144*nn+16*sg)
        }
    }
    // --- stage W transposed (vector global loads + LDS scatter) ---
    if (f32) {
        for (int idx = tid; idx < 1024; idx += 256) {
            int k = idx >> 4, sg = idx & 15;
            float4 v = *(const float4*)(Wf + k * 64 + sg * 4);
            wt[(sg * 4 + 0) * 72 + k] = f2b(v.x);
            wt[(sg * 4 + 1) * 72 + k] = f2b(v.y);
            wt[(sg * 4 + 2) * 72 + k] = f2b(v.z);
            wt[(sg * 4 + 3) * 72 + k] = f2b(v.w);
        }
    } else {
        for (int idx = tid; idx < 512; idx += 256) {
            int k = idx >> 3, sg = idx & 7;
            short8 v = *(const short8*)(Wb + k * 64 + sg * 8);
            #pragma unroll
            for (int j = 0; j < 8; ++j)
                wt[(sg * 8 + j) * 72 + k] = (unsigned short)v[j];
        }
    }
    __syncthreads();
    int lane = tid & 63, wid = tid >> 6;
    int m0 = wid * 16;
    int quad = lane >> 4, nl = lane & 15;
    short8 a0 = *(const short8*)(xs + (m0 + nl) * 72 + quad * 8);
    short8 a1 = *(const short8*)(xs + (m0 + nl) * 72 + quad * 8 + 32);
    floatx4 acc[4];
    #pragma unroll
    for (int ct = 0; ct < 4; ++ct) {
        int n = ct * 16 + nl;
        short8 b0 = *(const short8*)(wt + n * 72 + quad * 8);
        short8 b1 = *(const short8*)(wt + n * 72 + quad * 8 + 32);
        floatx4 c = {0.f, 0.f, 0.f, 0.f};
        c = __builtin_amdgcn_mfma_f32_16x16x32_bf16(a0, b0, c, 0, 0, 0);
        c = __builtin_amdgcn_mfma_f32_16x16x32_bf16(a1, b1, c, 0, 0, 0);
        acc[ct] = c;
    }
    #pragma unroll
    for (int r = 0; r < 4; ++r) {
        int node = n0 + m0 + quad * 4 + r;   // always < NPAD
        if (node < NN) {
            float dn = dis[node];
            #pragma unroll
            for (int ct = 0; ct < 4; ++ct)
                Hout[(long)node * 64 + ct * 16 + nl] = f2b(dn * acc[ct][r]);
        } else {                              // zero pad rows NN..NPAD-1
            #pragma unroll
            for (int ct = 0; ct < 4; ++ct)
                Hout[(long)node * 64 + ct * 16 + nl] = 0;
        }
    }
}

// ---------------- per-node aggregation + bias + relu + l2norm ----------------
// Padded CSR: per node, windows of 32 slots, all real-or-NN. Inner loop per
// lane: ONE uint4 index load (8 indices) + 8 gathers (128B rows, 8 lanes/edge)
// + 8 unpack-accumulates. No compares, no clamps, 8 gathers in flight.
__global__ void k_agg(const uint4* __restrict__ hp128, const int* __restrict__ rp0,
                      const int* __restrict__ degA, const float* __restrict__ dis,
                      const unsigned short* __restrict__ csr_col,
                      const void* __restrict__ bias, const int* __restrict__ flag,
                      unsigned short* __restrict__ eo /* [N,64] bf16 */) {
    int lane = threadIdx.x & 63, wid = threadIdx.x >> 6;
    int half = lane >> 5;
    int i = blockIdx.x * 8 + wid * 2 + half;
    bool valid = (i < NN);
    int iv = valid ? i : 0;
    int q4 = (lane >> 3) & 3;   // edge-slot octet within half
    int fl = lane & 7;          // feature octet 8fl..8fl+7
    float2 A0 = {0,0}, A1 = {0,0}, A2 = {0,0}, A3 = {0,0};
    #define ADDU(u) do { \
        A0.x += asf((u).x << 16); A0.y += asf((u).x & 0xFFFF0000u); \
        A1.x += asf((u).y << 16); A1.y += asf((u).y & 0xFFFF0000u); \
        A2.x += asf((u).z << 16); A2.y += asf((u).z & 0xFFFF0000u); \
        A3.x += asf((u).w << 16); A3.y += asf((u).w & 0xFFFF0000u); } while (0)
    if (valid && q4 == 0) {     // self-loop term
        uint4 u = hp128[(long)iv * 8 + fl];
        ADDU(u);
    }
    int e0 = rp0[iv];
    int pd = (degA[iv] + 31) & ~31;          // padded degree (multiple of 32)
    const unsigned short* cb = csr_col + e0 + q4 * 8;  // 16B-aligned
    for (int t = 0; t < pd; t += 32) {
        uint4 I = *(const uint4*)(cb + t);   // 8 u16 indices, broadcast over fl
        int c0 = (int)(I.x & 0xFFFFu), c1 = (int)(I.x >> 16);
        int c2 = (int)(I.y & 0xFFFFu), c3 = (int)(I.y >> 16);
        int c4 = (int)(I.z & 0xFFFFu), c5 = (int)(I.z >> 16);
        int c6 = (int)(I.w & 0xFFFFu), c7 = (int)(I.w >> 16);
        uint4 u0 = hp128[(long)c0 * 8 + fl];
        uint4 u1 = hp128[(long)c1 * 8 + fl];
        uint4 u2 = hp128[(long)c2 * 8 + fl];
        uint4 u3 = hp128[(long)c3 * 8 + fl];
        uint4 u4 = hp128[(long)c4 * 8 + fl];
        uint4 u5 = hp128[(long)c5 * 8 + fl];
        uint4 u6 = hp128[(long)c6 * 8 + fl];
        uint4 u7 = hp128[(long)c7 * 8 + fl];
        ADDU(u0); ADDU(u1); ADDU(u2); ADDU(u3);
        ADDU(u4); ADDU(u5); ADDU(u6); ADDU(u7);
    }
    #undef ADDU
    // reduce over the 4 q4 slots (lane bits 3,4)
    #pragma unroll
    for (int off = 8; off < 32; off <<= 1) {
        A0.x += __shfl_xor(A0.x, off); A0.y += __shfl_xor(A0.y, off);
        A1.x += __shfl_xor(A1.x, off); A1.y += __shfl_xor(A1.y, off);
        A2.x += __shfl_xor(A2.x, off); A2.y += __shfl_xor(A2.y, off);
        A3.x += __shfl_xor(A3.x, off); A3.y += __shfl_xor(A3.y, off);
    }
    const int f32 = flag[0];
    float di = dis[iv];
    float v0 = fmaf(di, A0.x, ldext(bias, 8 * fl + 0, f32));
    float v1 = fmaf(di, A0.y, ldext(bias, 8 * fl + 1, f32));
    float v2 = fmaf(di, A1.x, ldext(bias, 8 * fl + 2, f32));
    float v3 = fmaf(di, A1.y, ldext(bias, 8 * fl + 3, f32));
    float v4 = fmaf(di, A2.x, ldext(bias, 8 * fl + 4, f32));
    float v5 = fmaf(di, A2.y, ldext(bias, 8 * fl + 5, f32));
    float v6 = fmaf(di, A3.x, ldext(bias, 8 * fl + 6, f32));
    float v7 = fmaf(di, A3.y, ldext(bias, 8 * fl + 7, f32));
    v0 = fmaxf(v0, 0.f); v1 = fmaxf(v1, 0.f); v2 = fmaxf(v2, 0.f); v3 = fmaxf(v3, 0.f);
    v4 = fmaxf(v4, 0.f); v5 = fmaxf(v5, 0.f); v6 = fmaxf(v6, 0.f); v7 = fmaxf(v7, 0.f);
    float s = fmaf(v0, v0, fmaf(v1, v1, fmaf(v2, v2, v3 * v3)))
            + fmaf(v4, v4, fmaf(v5, v5, fmaf(v6, v6, v7 * v7)));
    #pragma unroll
    for (int off = 4; off; off >>= 1) s += __shfl_xor(s, off);
    float inv = 1.f / fmaxf(sqrtf(s), 1e-12f);
    if (valid && q4 == 0) {
        union { unsigned short us[8]; uint4 v; } pk;
        pk.us[0] = f2b(v0 * inv); pk.us[1] = f2b(v1 * inv);
        pk.us[2] = f2b(v2 * inv); pk.us[3] = f2b(v3 * inv);
        pk.us[4] = f2b(v4 * inv); pk.us[5] = f2b(v5 * inv);
        pk.us[6] = f2b(v6 * inv); pk.us[7] = f2b(v7 * inv);
        *(uint4*)(eo + (long)i * 64 + 8 * fl) = pk.v;
    }
}

// ---------------- head: emb @ Wlin + blin + log_softmax, MFMA ----------------
__global__ void k_out(const unsigned short* __restrict__ emb, const void* __restrict__ Wlin,
                      const void* __restrict__ blin, const int* __restrict__ flag,
                      void* __restrict__ out) {
    int tid = threadIdx.x, lane = tid & 63, wid = tid >> 6;
    int quad = lane >> 4, nl = lane & 15;
    int base = blockIdx.x * 64 + wid * 16;
    const int f32 = flag[0];
    const unsigned short* Wb = (const unsigned short*)Wlin;
    const float* Wf = (const float*)Wlin;
    int ia = min(base + nl, NN - 1);     // A-row node (guarded store later)
    floatx4 c = {0.f, 0.f, 0.f, 0.f};
    #pragma unroll
    for (int kc = 0; kc < 6; ++kc) {
        short8 b;
        #pragma unroll
        for (int j = 0; j < 8; ++j) {
            int k = kc * 32 + quad * 8 + j;
            b[j] = (short)(f32 ? f2b(Wf[k * 16 + nl]) : Wb[k * 16 + nl]);
        }
        int L = kc >> 1, ko = (kc & 1) * 32 + quad * 8;
        short8 a = *(const short8*)(emb + (long)L * NN * 64 + (long)ia * 64 + ko);
        c = __builtin_amdgcn_mfma_f32_16x16x32_bf16(a, b, c, 0, 0, 0);
    }
    float bl = ldext(blin, nl, f32);
    #pragma unroll
    for (int r = 0; r < 4; ++r) {
        float v = c[r] + bl;
        float m = v;
        #pragma unroll
        for (int off = 1; off < 16; off <<= 1) m = fmaxf(m, __shfl_xor(m, off));
        float ex = __expf(v - m);
        float s = ex;
        #pragma unroll
        for (int off = 1; off < 16; off <<= 1) s += __shfl_xor(s, off);
        float o = (v - m) - __logf(s);
        int node = base + quad * 4 + r;
        if (node < NN) {
            long oidx = (long)node * 16 + nl;
            if (f32) ((float*)out)[oidx] = o;
            else     ((__hip_bfloat16*)out)[oidx] = __float2bfloat16(o);
        }
    }
}

extern "C" void kernel_launch(void* const* d_in, const int* in_sizes, int n_in,
                              void* d_out, int out_size, void* d_ws, size_t ws_size,
                              hipStream_t stream) {
    const void* x    = d_in[0];
    const int*  ei   = (const int*)d_in[1];
    const void* W1   = d_in[2];
    const void* b1   = d_in[3];
    const void* W2   = d_in[4];
    const void* b2   = d_in[5];
    const void* W3   = d_in[6];
    const void* b3   = d_in[7];
    const void* Wlin = d_in[8];
    const void* blin = d_in[9];

    // workspace layout (~39.3 MB)
    unsigned short* h   = (unsigned short*)d_ws;      // NPAD*64 bf16 (rows >=NN zero)
    unsigned short* emb = h + (long)NPAD * 64;        // 3 x N*64 bf16 (normalized)
    float* dis     = (float*)(emb + (long)3 * NN * 64); // N
    int*   rp0     = (int*)(dis + NN);                // N  (padded CSR row starts)
    int*   degA    = rp0 + NN;                        // N  (real degrees)
    int*   flag    = degA + NN;                       // 16
    int*   bcur    = flag + 16;                       // NB*CPAD (line-padded)
    unsigned* bdata = (unsigned*)(bcur + NB * CPAD);  // NB*CAPB u32 (~7.2 MB)
    unsigned short* csr_col = (unsigned short*)(bdata + (long)NB * CAPB); // NB*PBCAP u16

    const int* row = ei;        // edge_index[0] = targets
    const int* col = ei + EE;   // edge_index[1] = sources

    (void)hipMemsetAsync(bcur, 0, NB * CPAD * sizeof(int), stream);
    k_bucket<<<(EE + EPB - 1) / EPB, 256, 0, stream>>>(row, col, bcur, bdata,
                                                       (const unsigned short*)x, flag);
    k_csr<<<NB, 256, 0, stream>>>(bcur, bdata, rp0, degA, dis, csr_col);

    int gb = (NN + 63) / 64;    // 782 blocks -> covers nodes 0..50047 (= NPAD)
    int ga = (NN + 7) / 8;      // 6250 blocks
    const uint4* hp128 = (const uint4*)h;
    // layer 1 (input: external x)
    k_gemm<true><<<gb, 256, 0, stream>>>(x, W1, flag, dis, h);
    k_agg<<<ga, 256, 0, stream>>>(hp128, rp0, degA, dis, csr_col, b1, flag, emb);
    // layer 2 (input: emb layer 0, bf16)
    k_gemm<false><<<gb, 256, 0, stream>>>(emb, W2, flag, dis, h);
    k_agg<<<ga, 256, 0, stream>>>(hp128, rp0, degA, dis, csr_col, b2, flag,
                                  emb + (long)NN * 64);
    // layer 3 (input: emb layer 1, bf16)
    k_gemm<false><<<gb, 256, 0, stream>>>(emb + (long)NN * 64, W3, flag, dis, h);
    k_agg<<<ga, 256, 0, stream>>>(hp128, rp0, degA, dis, csr_col, b3, flag,
                                  emb + (long)2 * NN * 64);

    k_out<<<gb, 256, 0, stream>>>(emb, Wlin, blin, flag, d_out);
}